// Round 1
// baseline (85.203 us; speedup 1.0000x reference)
//
#include <hip/hip_runtime.h>
#include <math.h>

// Problem constants (from reference): cost [B, D, H, W] fp32, k=2.
constexpr int B = 16, D = 48, H = 256, W = 512;
constexpr int HW = H * W;            // 131072 = 2^17
constexpr int PIX = B * HW;          // 2,097,152 pixels
constexpr int VEC = 4;               // float4 per thread
constexpr int NTHREADS = PIX / VEC;  // 524,288

__global__ __launch_bounds__(256) void topk2_disp_kernel(
    const float* __restrict__ cost, float* __restrict__ out) {
    const int tid = blockIdx.x * blockDim.x + threadIdx.x;   // one thread = 4 pixels
    const int p   = tid << 2;                                // pixel index (fits in int)
    const int b   = tid >> 15;                               // p / HW
    const int rem = p & (HW - 1);                            // p % HW

    const float* base = cost + (size_t)b * D * HW + rem;

    float v1[VEC], v2[VEC];
    int   i1[VEC], i2[VEC];
#pragma unroll
    for (int j = 0; j < VEC; ++j) {
        v1[j] = -INFINITY; v2[j] = -INFINITY; i1[j] = 0; i2[j] = 0;
    }

#pragma unroll
    for (int d = 0; d < D; ++d) {
        float4 v = *reinterpret_cast<const float4*>(base + (size_t)d * HW);
        float vv[VEC] = {v.x, v.y, v.z, v.w};
#pragma unroll
        for (int j = 0; j < VEC; ++j) {
            const float x = vv[j];
            // strict > : ties keep the earlier (lower) index, matching lax.top_k
            if (x > v1[j]) {
                v2[j] = v1[j]; i2[j] = i1[j];
                v1[j] = x;     i1[j] = d;
            } else if (x > v2[j]) {
                v2[j] = x;     i2[j] = d;
            }
        }
    }

    float4 o;
    float res[VEC];
#pragma unroll
    for (int j = 0; j < VEC; ++j) {
        // softmax over [v1, v2] with v1 >= v2:
        //   w1 = 1/(1+e), w2 = e/(1+e), e = exp(v2 - v1)
        const float e   = expf(v2[j] - v1[j]);
        const float inv = 1.0f / (1.0f + e);
        res[j] = ((float)i1[j] + e * (float)i2[j]) * inv;
    }
    o.x = res[0]; o.y = res[1]; o.z = res[2]; o.w = res[3];
    *reinterpret_cast<float4*>(out + p) = o;
}

extern "C" void kernel_launch(void* const* d_in, const int* in_sizes, int n_in,
                              void* d_out, int out_size, void* d_ws, size_t ws_size,
                              hipStream_t stream) {
    const float* cost = (const float*)d_in[0];
    // d_in[1] is k (always 2 for this problem; hard-coded top-2 path)
    float* out = (float*)d_out;

    constexpr int BLOCK = 256;
    constexpr int GRID  = NTHREADS / BLOCK;  // 2048
    topk2_disp_kernel<<<GRID, BLOCK, 0, stream>>>(cost, out);
}

// Round 3
// 83.137 us; speedup vs baseline: 1.0248x; 1.0248x over previous
//
#include <hip/hip_runtime.h>
#include <math.h>

// Problem constants (from reference): cost [B, D, H, W] fp32, k=2.
constexpr int B = 16, D = 48, H = 256, W = 512;
constexpr int HW = H * W;            // 131072 = 2^17
constexpr int PIX = B * HW;          // 2,097,152 pixels
constexpr int VEC = 8;               // 8 pixels (2x float4) per thread
constexpr int NTHREADS = PIX / VEC;  // 262,144

// clang native vector type — required by __builtin_nontemporal_load/store
typedef float f32x4 __attribute__((ext_vector_type(4)));

__global__ __launch_bounds__(256) void topk2_disp_kernel(
    const float* __restrict__ cost, float* __restrict__ out) {
    const int tid = blockIdx.x * blockDim.x + threadIdx.x;   // one thread = 8 pixels
    const int p   = tid << 3;                                // pixel index
    const int b   = p >> 17;                                 // p / HW
    const int rem = p & (HW - 1);                            // p % HW

    const float* base = cost + (size_t)b * D * HW + rem;

    float v1[VEC], v2[VEC];
    int   i1[VEC], i2[VEC];
#pragma unroll
    for (int j = 0; j < VEC; ++j) {
        v1[j] = -INFINITY; v2[j] = -INFINITY; i1[j] = 0; i2[j] = 0;
    }

#pragma unroll
    for (int d = 0; d < D; ++d) {
        const float* row = base + (size_t)d * HW;
        const f32x4 a = __builtin_nontemporal_load(reinterpret_cast<const f32x4*>(row));
        const f32x4 c = __builtin_nontemporal_load(reinterpret_cast<const f32x4*>(row + 4));
        float vv[VEC] = {a.x, a.y, a.z, a.w, c.x, c.y, c.z, c.w};
#pragma unroll
        for (int j = 0; j < VEC; ++j) {
            const float x = vv[j];
            // strict > : ties keep the earlier (lower) index, matching lax.top_k
            if (x > v1[j]) {
                v2[j] = v1[j]; i2[j] = i1[j];
                v1[j] = x;     i1[j] = d;
            } else if (x > v2[j]) {
                v2[j] = x;     i2[j] = d;
            }
        }
    }

    float res[VEC];
#pragma unroll
    for (int j = 0; j < VEC; ++j) {
        // softmax over [v1, v2] with v1 >= v2:
        //   w1 = 1/(1+e), w2 = e/(1+e), e = exp(v2 - v1)
        const float e   = expf(v2[j] - v1[j]);
        const float inv = 1.0f / (1.0f + e);
        res[j] = ((float)i1[j] + e * (float)i2[j]) * inv;
    }
    f32x4 o0, o1;
    o0.x = res[0]; o0.y = res[1]; o0.z = res[2]; o0.w = res[3];
    o1.x = res[4]; o1.y = res[5]; o1.z = res[6]; o1.w = res[7];
    __builtin_nontemporal_store(o0, reinterpret_cast<f32x4*>(out + p));
    __builtin_nontemporal_store(o1, reinterpret_cast<f32x4*>(out + p + 4));
}

extern "C" void kernel_launch(void* const* d_in, const int* in_sizes, int n_in,
                              void* d_out, int out_size, void* d_ws, size_t ws_size,
                              hipStream_t stream) {
    const float* cost = (const float*)d_in[0];
    // d_in[1] is k (always 2 for this problem; hard-coded top-2 path)
    float* out = (float*)d_out;

    constexpr int BLOCK = 256;
    constexpr int GRID  = NTHREADS / BLOCK;  // 1024
    topk2_disp_kernel<<<GRID, BLOCK, 0, stream>>>(cost, out);
}